// Round 8
// baseline (77.974 us; speedup 1.0000x reference)
//
#include <hip/hip_runtime.h>
#include <hip/hip_fp16.h>
#include <cstdint>
#include <cstddef>

#define B_ 8
#define N_ 256
#define D_ 128
#define H_ 128
#define K_ 8

typedef _Float16 f16x8 __attribute__((ext_vector_type(8)));
typedef float    f32x4 __attribute__((ext_vector_type(4)));

static __device__ __forceinline__ unsigned packh2(float lo, float hi) {
    unsigned a = __half_as_ushort(__float2half(lo));
    unsigned b = __half_as_ushort(__float2half(hi));
    return a | (b << 16);
}

// ---------------------------------------------------------------------------
// prep_all: [0,256): Eh = fp16(E)
//           [256,320): Wh[k][c][d] = fp16( W1[k][(c<128? d:128+d)][c&127] )
//           320: wh05 = 0.5*(W2[:,0]-W2[:,1]); consts = {cu, w3d, w3b}
//                cu = b2d + sum_h wh05*b1
// ---------------------------------------------------------------------------
__global__ __launch_bounds__(256) void prep_all(
        const float* __restrict__ E, const float* __restrict__ W1,
        const float* __restrict__ b1g, const float* __restrict__ W2,
        const float* __restrict__ b2, const float* __restrict__ W3,
        const float* __restrict__ b3,
        __half* __restrict__ Eh, __half* __restrict__ Wh,
        float* __restrict__ wh05, float* __restrict__ consts) {
    __shared__ float Ws[128][33];
    __shared__ float wtmp[K_ * H_];
    const int bid = blockIdx.x;
    const int t   = threadIdx.x;

    if (bid < 256) {
        int idx = (bid * 256 + t) * 4;
        float4 v = *(const float4*)&E[idx];
        uint2 o;
        o.x = packh2(v.x, v.y);
        o.y = packh2(v.z, v.w);
        *(uint2*)&Eh[idx] = o;
    } else if (bid < 320) {
        const int kb = bid - 256;
        const int ct = kb & 7;
        const int k  = kb >> 3;
        const int c0 = ct * 32;
        const int ro = (c0 < 128) ? 0 : 128;
        const int h0 = c0 & 127;
        #pragma unroll
        for (int rep = 0; rep < 16; rep++) {
            int idx = rep * 256 + t;
            int d   = idx >> 5;
            int cl  = idx & 31;
            Ws[d][cl] = W1[((size_t)(k * 256 + ro + d)) * H_ + h0 + cl];
        }
        __syncthreads();
        const int cl = t >> 3;   // 0..31
        const int dg = t & 7;    // 0..7 (16 d each)
        __half tmp[16];
        #pragma unroll
        for (int e = 0; e < 16; e++) tmp[e] = __float2half(Ws[dg * 16 + e][cl]);
        *(float4*)&Wh[((size_t)(k * 256 + c0 + cl)) * D_ + dg * 16]     = *(float4*)&tmp[0];
        *(float4*)&Wh[((size_t)(k * 256 + c0 + cl)) * D_ + dg * 16 + 8] = *(float4*)&tmp[8];
    } else {
        for (int idx = t; idx < K_ * H_; idx += 256) {
            float w = 0.5f * (W2[idx * 2] - W2[idx * 2 + 1]);
            wtmp[idx] = w;
            wh05[idx] = w;
        }
        __syncthreads();
        if (t < K_) {
            float cu = b2[t * 2] - b2[t * 2 + 1];
            for (int h = 0; h < H_; h++)
                cu += wtmp[t * H_ + h] * b1g[t * H_ + h];
            consts[t * 4 + 0] = cu;
            consts[t * 4 + 1] = W3[t * 2] - W3[t * 2 + 1];
            consts[t * 4 + 2] = W3[t * 2 + 1] + b3[t];
        }
    }
}

// ---------------------------------------------------------------------------
// fused v4: block = (bk, 64i x 64j). LDS 52.7 KB -> 3 blocks/CU.
//  stage A (MFMA): a_lds[64][132] f32 = Ei@W1i + b1 ; b_lds[64][136] fp16 = Ej@W1j
//  u/v pass (2 waves): u_i = cu + dot(a_i, wh05); v_j = dot(b_j, wh05)
//  stage B (2 f32 ops/h): acc += wh05_h * |a_ih + b_jh| ; T = u_i + v_j + acc
//  (identity: sum_h w*relu(p) = sum 0.5w*p + sum 0.5w*|p|, exact in-block)
// ---------------------------------------------------------------------------
__global__ __launch_bounds__(256, 3) void fused_kernel(
        const __half* __restrict__ Eh, const __half* __restrict__ Wh,
        const float* __restrict__ b1g, const float* __restrict__ wh05,
        const float* __restrict__ consts, float* __restrict__ out) {
    __shared__ float  a_lds[64 * 132];
    __shared__ __half b_lds[64 * 136];
    __shared__ float  wlds[128];
    __shared__ float  b1lds[128];
    __shared__ float  ulds[64];
    __shared__ float  vlds[64];

    const int bid = blockIdx.x;
    const int jt  = bid & 3;
    const int it  = (bid >> 2) & 3;
    const int bk  = bid >> 4;
    const int k   = bk & (K_ - 1);
    const int b   = bk >> 3;
    const int i0  = it * 64, j0 = jt * 64;
    const int t   = threadIdx.x;
    const int wv   = t >> 6;
    const int lane = t & 63;
    const int lr   = lane & 15, lk = lane >> 4;

    if (t < 128) {
        wlds[t]  = wh05[k * H_ + t];
        b1lds[t] = b1g[k * H_ + t];
    }
    __syncthreads();

    // ---- stage A: MFMA -> a_lds (f32, +b1) and b_lds (fp16) ----
    #pragma unroll
    for (int rb = 0; rb < 2; rb++) {
        const int grp  = wv * 2 + rb;                 // 0..7
        const bool isJ = (grp >= 4);
        const int rowg = (isJ ? j0 + (grp - 4) * 16 : i0 + grp * 16) + lr;
        const int cbase = isJ ? 128 : 0;

        f16x8 A[4];
        #pragma unroll
        for (int kk = 0; kk < 4; kk++)
            A[kk] = *(const f16x8*)&Eh[((size_t)(b * N_ + rowg)) * D_ + kk * 32 + lk * 8];

        #pragma unroll
        for (int nc = 0; nc < 8; nc++) {
            f16x8 Bf[4];
            #pragma unroll
            for (int kk = 0; kk < 4; kk++)
                Bf[kk] = *(const f16x8*)&Wh[
                    ((size_t)(k * 256 + cbase + nc * 16 + lr)) * D_ + kk * 32 + lk * 8];
            const int hcol = nc * 16 + lr;
            f32x4 acc = {0.f, 0.f, 0.f, 0.f};
            #pragma unroll
            for (int kk = 0; kk < 4; kk++)
                acc = __builtin_amdgcn_mfma_f32_16x16x32_f16(A[kk], Bf[kk], acc, 0, 0, 0);
            if (isJ) {
                #pragma unroll
                for (int q = 0; q < 4; q++)
                    b_lds[((grp - 4) * 16 + lk * 4 + q) * 136 + hcol] = __float2half(acc[q]);
            } else {
                const float bias = b1lds[hcol];
                #pragma unroll
                for (int q = 0; q < 4; q++)
                    a_lds[(grp * 16 + lk * 4 + q) * 132 + hcol] = acc[q] + bias;
            }
        }
    }
    __syncthreads();

    // ---- u/v pass: rank-1 dots from the SAME tiles (exact identity) ----
    if (t < 64) {
        float s = consts[k * 4 + 0];   // cu
        #pragma unroll
        for (int hq = 0; hq < 16; hq++) {
            float4 a0 = *(const float4*)&a_lds[t * 132 + hq * 8];
            float4 a1 = *(const float4*)&a_lds[t * 132 + hq * 8 + 4];
            s += a0.x * wlds[hq * 8 + 0] + a0.y * wlds[hq * 8 + 1]
               + a0.z * wlds[hq * 8 + 2] + a0.w * wlds[hq * 8 + 3]
               + a1.x * wlds[hq * 8 + 4] + a1.y * wlds[hq * 8 + 5]
               + a1.z * wlds[hq * 8 + 6] + a1.w * wlds[hq * 8 + 7];
        }
        ulds[t] = s;
    } else if (t < 128) {
        const int r = t - 64;
        float s = 0.f;
        #pragma unroll
        for (int hq = 0; hq < 16; hq++) {
            f16x8 bv = *(const f16x8*)&b_lds[r * 136 + hq * 8];
            #pragma unroll
            for (int e = 0; e < 8; e++) s += (float)bv[e] * wlds[hq * 8 + e];
        }
        vlds[r] = s;
    }
    __syncthreads();

    // ---- stage B: 2-op inner loop over h ----
    const float w3d = consts[k * 4 + 1];
    const float w3b = consts[k * 4 + 2];
    const int tx = t & 15;   // j = j0 + tx + 16c
    const int ty = t >> 4;   // i = i0 + ty + 16a

    float acc[4][4];
    #pragma unroll
    for (int a = 0; a < 4; a++)
        #pragma unroll
        for (int c = 0; c < 4; c++) acc[a][c] = 0.f;

    for (int hq = 0; hq < 16; hq++) {   // 8 h per iter; body kept small (rolled)
        float ws8[8];
        *(float4*)&ws8[0] = *(const float4*)&wlds[hq * 8];
        *(float4*)&ws8[4] = *(const float4*)&wlds[hq * 8 + 4];
        float Af[4][8];
        #pragma unroll
        for (int a = 0; a < 4; a++) {
            *(float4*)&Af[a][0] = *(const float4*)&a_lds[(ty + 16 * a) * 132 + hq * 8];
            *(float4*)&Af[a][4] = *(const float4*)&a_lds[(ty + 16 * a) * 132 + hq * 8 + 4];
        }
        f16x8 Bh[4];
        #pragma unroll
        for (int c = 0; c < 4; c++)
            Bh[c] = *(const f16x8*)&b_lds[(tx + 16 * c) * 136 + hq * 8];

        #pragma unroll
        for (int e = 0; e < 8; e++) {
            float bf[4];
            #pragma unroll
            for (int c = 0; c < 4; c++) bf[c] = (float)Bh[c][e];
            #pragma unroll
            for (int a = 0; a < 4; a++)
                #pragma unroll
                for (int c = 0; c < 4; c++)
                    acc[a][c] = fmaf(ws8[e], fabsf(Af[a][e] + bf[c]), acc[a][c]);
        }
    }

    // ---- epilogue: T = u + v + acc ; entmax15 closed form ; diagonal ----
    float ua[4], vc[4];
    #pragma unroll
    for (int a = 0; a < 4; a++) ua[a] = ulds[ty + 16 * a];
    #pragma unroll
    for (int c = 0; c < 4; c++) vc[c] = vlds[tx + 16 * c];

    #pragma unroll
    for (int a = 0; a < 4; a++) {
        const int i = i0 + ty + 16 * a;
        #pragma unroll
        for (int c = 0; c < 4; c++) {
            float T = ua[a] + vc[c] + acc[a][c];
            float tt = T * 0.25f;
            float dd = fabsf(tt);
            float ss = sqrtf(fmaxf(0.5f - dd * dd, 0.f));
            float p0i = (ss + tt) * (ss + tt);
            float p0 = (dd >= 0.5f) ? (tt > 0.f ? 1.f : 0.f) : p0i;
            float val = fmaf(p0, w3d, w3b);
            const int j = j0 + tx + 16 * c;
            if (i == j) val = 0.f;
            out[((size_t)bk * N_ + i) * N_ + j] = val;
        }
    }
}

// ---------------------------------------------------------------------------
extern "C" void kernel_launch(void* const* d_in, const int* in_sizes, int n_in,
                              void* d_out, int out_size, void* d_ws, size_t ws_size,
                              hipStream_t stream) {
    (void)in_sizes; (void)n_in; (void)out_size; (void)ws_size;
    const float* E  = (const float*)d_in[0];
    const float* W1 = (const float*)d_in[1];
    const float* b1 = (const float*)d_in[2];
    const float* W2 = (const float*)d_in[3];
    const float* b2 = (const float*)d_in[4];
    const float* W3 = (const float*)d_in[5];
    const float* b3 = (const float*)d_in[6];
    float* out = (float*)d_out;

    char* ws = (char*)d_ws;
    float*  wh05   = (float*)ws;                           // K*H f32 = 4 KB
    float*  consts = (float*)(ws + 4096);                  // K*4 floats
    __half* Eh     = (__half*)(ws + 8192);                 // 512 KB
    __half* Wh     = (__half*)(ws + 8192 + 524288);        // 512 KB

    prep_all<<<321, 256, 0, stream>>>(E, W1, b1, W2, b2, W3, b3, Eh, Wh, wh05, consts);
    fused_kernel<<<B_ * K_ * 16, 256, 0, stream>>>(Eh, Wh, b1, wh05, consts, out);
}

// Round 9
// 57.306 us; speedup vs baseline: 1.3607x; 1.3607x over previous
//
#include <hip/hip_runtime.h>
#include <hip/hip_fp16.h>
#include <cstdint>
#include <cstddef>

#define B_ 8
#define N_ 256
#define D_ 128
#define H_ 128
#define K_ 8

typedef _Float16 f16x8 __attribute__((ext_vector_type(8)));
typedef _Float16 f16x2 __attribute__((ext_vector_type(2)));
typedef float    f32x4 __attribute__((ext_vector_type(4)));

static __device__ __forceinline__ f16x2 h2cast(unsigned u) {
    return __builtin_bit_cast(f16x2, u);
}
static __device__ __forceinline__ unsigned packh2(float lo, float hi) {
    unsigned a = __half_as_ushort(__float2half(lo));
    unsigned b = __half_as_ushort(__float2half(hi));
    return a | (b << 16);
}

// ---------------------------------------------------------------------------
// prep_all: [0,256): Eh = fp16(E)
//           [256,320): Wh[k][c][d] = fp16( W1[k][(c<128? d:128+d)][c&127] )
//           320: wdh (half2 of W2 col-diff) + consts {b2d, w3d, w3b}
// ---------------------------------------------------------------------------
__global__ __launch_bounds__(256) void prep_all(
        const float* __restrict__ E, const float* __restrict__ W1,
        const float* __restrict__ W2, const float* __restrict__ b2,
        const float* __restrict__ W3, const float* __restrict__ b3,
        __half* __restrict__ Eh, __half* __restrict__ Wh,
        unsigned* __restrict__ wdh, float* __restrict__ consts) {
    __shared__ float Ws[128][33];
    const int bid = blockIdx.x;
    const int t   = threadIdx.x;

    if (bid < 256) {
        int idx = (bid * 256 + t) * 4;
        float4 v = *(const float4*)&E[idx];
        uint2 o;
        o.x = packh2(v.x, v.y);
        o.y = packh2(v.z, v.w);
        *(uint2*)&Eh[idx] = o;
    } else if (bid < 320) {
        const int kb = bid - 256;
        const int ct = kb & 7;
        const int k  = kb >> 3;
        const int c0 = ct * 32;
        const int ro = (c0 < 128) ? 0 : 128;
        const int h0 = c0 & 127;
        #pragma unroll
        for (int rep = 0; rep < 16; rep++) {
            int idx = rep * 256 + t;
            int d   = idx >> 5;
            int cl  = idx & 31;
            Ws[d][cl] = W1[((size_t)(k * 256 + ro + d)) * H_ + h0 + cl];
        }
        __syncthreads();
        const int cl = t >> 3;   // 0..31
        const int dg = t & 7;    // 0..7 (16 d each)
        __half tmp[16];
        #pragma unroll
        for (int e = 0; e < 16; e++) tmp[e] = __float2half(Ws[dg * 16 + e][cl]);
        *(float4*)&Wh[((size_t)(k * 256 + c0 + cl)) * D_ + dg * 16]     = *(float4*)&tmp[0];
        *(float4*)&Wh[((size_t)(k * 256 + c0 + cl)) * D_ + dg * 16 + 8] = *(float4*)&tmp[8];
    } else {
        for (int idx = t; idx < K_ * 64; idx += 256) {  // idx = k*64 + hh
            int base = idx * 2;
            float w0 = W2[base * 2]     - W2[base * 2 + 1];
            float w1 = W2[base * 2 + 2] - W2[base * 2 + 3];
            wdh[idx] = packh2(w0, w1);
        }
        if (t < K_) {
            consts[t * 4 + 0] = b2[t * 2] - b2[t * 2 + 1];
            consts[t * 4 + 1] = W3[t * 2] - W3[t * 2 + 1];
            consts[t * 4 + 2] = W3[t * 2 + 1] + b3[t];
        }
    }
}

// ---------------------------------------------------------------------------
// fused v5: R4 structure at FULL occupancy. 512-thread blocks, 64x64 tile,
// LDS 34.9 KB -> 4 blocks/CU x 8 waves = 32 waves/CU.
//   stage A (MFMA): wave w -> row-group w (waves 0-3: hi rows, 4-7: hj rows)
//   stage B (VALU): 2x4 micro-tile/thread, pk_add + pk_max + fdot2
// ---------------------------------------------------------------------------
__global__ __launch_bounds__(512, 8) void fused_kernel(
        const __half* __restrict__ Eh, const __half* __restrict__ Wh,
        const float* __restrict__ b1, const unsigned* __restrict__ wdh,
        const float* __restrict__ consts, float* __restrict__ out) {
    __shared__ __attribute__((aligned(16))) __half his[64 * 136];
    __shared__ __attribute__((aligned(16))) __half hjs[64 * 136];
    __shared__ __attribute__((aligned(16))) unsigned wlds[64];

    const int bid = blockIdx.x;
    const int jt  = bid & 3;
    const int it  = (bid >> 2) & 3;
    const int bk  = bid >> 4;
    const int k   = bk & (K_ - 1);
    const int b   = bk >> 3;
    const int i0  = it * 64, j0 = jt * 64;
    const int t   = threadIdx.x;
    const int wv   = t >> 6;        // 0..7
    const int lane = t & 63;
    const int lr   = lane & 15, lk = lane >> 4;

    if (t < 64) wlds[t] = wdh[k * 64 + t];

    // ---- stage A: one 16-row group per wave ----
    {
        const bool isJ  = (wv >= 4);
        const int  grp  = isJ ? (wv - 4) : wv;          // 0..3
        const int  rowg = (isJ ? j0 : i0) + grp * 16 + lr;
        const int  cbase = isJ ? 128 : 0;
        __half* __restrict__ dst = isJ ? hjs : his;

        f16x8 A[4];
        #pragma unroll
        for (int kk = 0; kk < 4; kk++)
            A[kk] = *(const f16x8*)&Eh[((size_t)(b * N_ + rowg)) * D_ + kk * 32 + lk * 8];

        #pragma unroll
        for (int nc = 0; nc < 8; nc++) {
            f16x8 Bf[4];
            #pragma unroll
            for (int kk = 0; kk < 4; kk++)
                Bf[kk] = *(const f16x8*)&Wh[
                    ((size_t)(k * 256 + cbase + nc * 16 + lr)) * D_ + kk * 32 + lk * 8];
            const int hcol = nc * 16 + lr;
            const float bias = isJ ? 0.f : b1[k * H_ + hcol];
            f32x4 acc = {0.f, 0.f, 0.f, 0.f};
            #pragma unroll
            for (int kk = 0; kk < 4; kk++)
                acc = __builtin_amdgcn_mfma_f32_16x16x32_f16(A[kk], Bf[kk], acc, 0, 0, 0);
            #pragma unroll
            for (int q = 0; q < 4; q++)
                dst[(grp * 16 + lk * 4 + q) * 136 + hcol] = __float2half(acc[q] + bias);
        }
    }
    __syncthreads();

    // ---- stage B: pairwise packed-f16 relu-dot, 2x4 outputs/thread ----
    const float b2d = consts[k * 4 + 0];
    const float w3d = consts[k * 4 + 1];
    const float w3b = consts[k * 4 + 2];
    const int tx  = t & 15;   // j = j0 + tx + 16c, c in 0..3
    const int tyy = t >> 4;   // i = i0 + tyy + 32a, a in 0..1

    float acc[2][4];
    #pragma unroll
    for (int a = 0; a < 2; a++)
        #pragma unroll
        for (int c = 0; c < 4; c++) acc[a][c] = b2d;

    const f16x2 zz = {(_Float16)0, (_Float16)0};

    #pragma unroll 2
    for (int hq = 0; hq < 16; hq++) {   // 8 h per iter
        unsigned Wv[4];
        *(uint4*)&Wv[0] = *(const uint4*)&wlds[hq * 4];
        unsigned Aa[2][4], Bb[4][4];
        #pragma unroll
        for (int a = 0; a < 2; a++)
            *(uint4*)&Aa[a][0] = *(const uint4*)&his[(tyy + 32 * a) * 136 + hq * 8];
        #pragma unroll
        for (int c = 0; c < 4; c++)
            *(uint4*)&Bb[c][0] = *(const uint4*)&hjs[(tx + 16 * c) * 136 + hq * 8];

        #pragma unroll
        for (int e = 0; e < 4; e++) {
            f16x2 w2 = h2cast(Wv[e]);
            #pragma unroll
            for (int a = 0; a < 2; a++) {
                f16x2 av = h2cast(Aa[a][e]);
                #pragma unroll
                for (int c = 0; c < 4; c++) {
                    f16x2 pre = av + h2cast(Bb[c][e]);
                    f16x2 act = __builtin_elementwise_max(pre, zz);
                    acc[a][c] = __builtin_amdgcn_fdot2(act, w2, acc[a][c], false);
                }
            }
        }
    }

    // ---- epilogue: entmax15 closed form + diagonal ----
    #pragma unroll
    for (int a = 0; a < 2; a++) {
        const int i = i0 + tyy + 32 * a;
        #pragma unroll
        for (int c = 0; c < 4; c++) {
            float av = acc[a][c];
            float tt = av * 0.25f;
            float dd = fabsf(tt);
            float ss = sqrtf(fmaxf(0.5f - dd * dd, 0.f));
            float p0i = (ss + tt) * (ss + tt);
            float p0 = (dd >= 0.5f) ? (tt > 0.f ? 1.f : 0.f) : p0i;
            float val = fmaf(p0, w3d, w3b);
            const int j = j0 + tx + 16 * c;
            if (i == j) val = 0.f;
            out[((size_t)bk * N_ + i) * N_ + j] = val;
        }
    }
}

// ---------------------------------------------------------------------------
extern "C" void kernel_launch(void* const* d_in, const int* in_sizes, int n_in,
                              void* d_out, int out_size, void* d_ws, size_t ws_size,
                              hipStream_t stream) {
    (void)in_sizes; (void)n_in; (void)out_size; (void)ws_size;
    const float* E  = (const float*)d_in[0];
    const float* W1 = (const float*)d_in[1];
    const float* b1 = (const float*)d_in[2];
    const float* W2 = (const float*)d_in[3];
    const float* b2 = (const float*)d_in[4];
    const float* W3 = (const float*)d_in[5];
    const float* b3 = (const float*)d_in[6];
    float* out = (float*)d_out;

    char* ws = (char*)d_ws;
    unsigned* wdh    = (unsigned*)ws;                    // K*64 half2 = 2 KB
    float*    consts = (float*)(ws + 4096);              // K*4 floats
    __half*   Eh     = (__half*)(ws + 8192);             // 512 KB
    __half*   Wh     = (__half*)(ws + 8192 + 524288);    // 512 KB

    prep_all<<<321, 256, 0, stream>>>(E, W1, W2, b2, W3, b3, Eh, Wh, wdh, consts);
    fused_kernel<<<B_ * K_ * 16, 512, 0, stream>>>(Eh, Wh, b1, wdh, consts, out);
}